// Round 24
// baseline (175.129 us; speedup 1.0000x reference)
//
#include <hip/hip_runtime.h>
#include <cmath>

// Problem constants (fixed by the reference file)
#define B_   8
#define N_   512
#define D_   1024
#define H_   16
#define HD_  64
#define NI_  4
#define BN_  (B_*N_)      // 4096 rows when [B,N,*] is flattened
#define KVLEN (NI_*N_)    // 2048 keys per attention group

typedef __attribute__((ext_vector_type(8)))  short  bf16x8;   // 8 bf16 bit patterns
typedef __attribute__((ext_vector_type(8)))  __bf16 bf16x8_t; // builtin operand type
typedef __attribute__((ext_vector_type(16))) float  f32x16;
typedef __attribute__((ext_vector_type(4)))  short  s16x4;
typedef __attribute__((ext_vector_type(2)))  unsigned u32x2;

// round-to-nearest-even bf16 conversion (bit trick)
__device__ __forceinline__ short bf16_rn(float x) {
  unsigned u = __float_as_uint(x);
  unsigned r = (u + 0x7FFFu + ((u >> 16) & 1u)) >> 16;
  return (short)r;
}

__device__ __forceinline__ float bf2f(short x) {
  return __uint_as_float(((unsigned)(unsigned short)x) << 16);
}

__device__ __forceinline__ f32x16 mfma_bf16(bf16x8 a, bf16x8 b, f32x16 c) {
  return __builtin_amdgcn_mfma_f32_32x32x16_bf16(
      __builtin_bit_cast(bf16x8_t, a), __builtin_bit_cast(bf16x8_t, b), c, 0, 0, 0);
}

#define GLOAD16(gp, lp) __builtin_amdgcn_global_load_lds( \
  (const __attribute__((address_space(1))) unsigned*)(gp), \
  (__attribute__((address_space(3))) unsigned*)(lp), 16, 0, 0)

// TILED layout for all bf16 GEMM operands (K = 1024):
// addr(row,k) = (((row>>7)*128 + (k>>3))*128 + (row&127))*8 + (k&7).
// GEMM staging is then a LINEAR copy -> fully coalesced global_load_lds.
__device__ __forceinline__ long tiled_off(int row, int k) {
  return ((((long)(row >> 7) * 128 + (k >> 3)) * 128 + (row & 127)) * 8 + (k & 7));
}

// T1 XCD-aware block swizzle (MI355X: 8 XCDs, private L2s). Remap so each
// XCD gets a CONTIGUOUS tile range. REQUIRES nwg % 8 == 0.
__device__ __forceinline__ void xcd_swizzle(int& bx, int& by, int& bz) {
  const int gx = gridDim.x, gy = gridDim.y;
  const int nwg = gx * gy * gridDim.z;
  const int lin = blockIdx.x + gx * (blockIdx.y + gy * blockIdx.z);
  const int swz = (lin & 7) * (nwg >> 3) + (lin >> 3);
  bx = swz % gx;
  const int rest = swz / gx;
  by = rest % gy;
  bz = rest / gy;
}

// =====================================================================
// Weight + x + gate-prep-A, ONE dispatch (z=0..8):
//  z=0..2: Wq/Wk/Wv -> QKVh (combined [3072][1024] tiled, transposed)
//  z=3:    Wo -> WoH (tiled, transposed)
//  z=4..7: x rows (z-4)*1024.. -> Xh (tiled, direct convert)
//  z=8:    fprep (gate rank-5 prep A) folded in: the 256-block plane
//          maps fid=by*16+bx -> (d-block fid&3, e-chunk fid>>2);
//          F4p[eb][j][d] = sum_{e in 16-chunk} emb[j][e]*Wik[e][d].
// =====================================================================
__global__ __launch_bounds__(256) void wsplitAll(
    const float* __restrict__ Wq, const float* __restrict__ Wk,
    const float* __restrict__ Wv, const float* __restrict__ Wo,
    const float* __restrict__ x,
    const float* __restrict__ Wik, const float* __restrict__ emb,
    short* __restrict__ QKVh, short* __restrict__ WoH,
    short* __restrict__ Xh, float* __restrict__ F4p)
{
  const int z = blockIdx.z;
  const int t  = threadIdx.x;
  if (z == 8) {
    const int fid = blockIdx.y * 16 + blockIdx.x;   // 0..255
    const int d  = (fid & 3) * 256 + t;
    const int eb = fid >> 2;
    float s0 = 0, s1 = 0, s2 = 0, s3 = 0;
    for (int e = eb * 16; e < eb * 16 + 16; e++) {
      const float w = Wik[(long)e * D_ + d];
      s0 = fmaf(emb[e], w, s0);
      s1 = fmaf(emb[D_ + e], w, s1);
      s2 = fmaf(emb[2 * D_ + e], w, s2);
      s3 = fmaf(emb[3 * D_ + e], w, s3);
    }
    float* p = F4p + (long)eb * 4 * D_;
    p[d] = s0;  p[D_ + d] = s1;  p[2 * D_ + d] = s2;  p[3 * D_ + d] = s3;
    return;
  }
  if (z >= 4) {
    const int rowB = (z - 4) * 1024 + blockIdx.y * 64;
    const int colB = blockIdx.x * 64;
    const int r0 = t >> 4;
    const int c4 = t & 15;
    #pragma unroll
    for (int i = 0; i < 4; i++) {
      const int row = rowB + r0 + i * 16;
      float4 v = *(const float4*)&x[(long)row * D_ + colB + c4 * 4];
      short h[4];
      h[0] = bf16_rn(v.x);  h[1] = bf16_rn(v.y);
      h[2] = bf16_rn(v.z);  h[3] = bf16_rn(v.w);
      *(s16x4*)&Xh[tiled_off(row, colB + c4 * 4)] = *(s16x4*)h;
    }
    return;
  }
  __shared__ float tile[64][65];
  const float* W = (z == 0) ? Wq : (z == 1) ? Wk : (z == 2) ? Wv : Wo;
  const int kb = blockIdx.y * 64;
  const int cb = blockIdx.x * 64;
  const int r0 = t >> 4;
  const int c4 = t & 15;
  #pragma unroll
  for (int i = 0; i < 4; i++) {
    const int r = r0 + i * 16;
    *(float4*)&tile[r][c4 * 4] = *(const float4*)&W[(long)(kb + r) * D_ + cb + c4 * 4];
  }
  __syncthreads();
  #pragma unroll
  for (int i = 0; i < 4; i++) {
    const int c = r0 + i * 16;
    short hi[4];
    #pragma unroll
    for (int e = 0; e < 4; e++)
      hi[e] = bf16_rn(tile[c4 * 4 + e][c]);
    if (z < 3)
      *(s16x4*)&QKVh[tiled_off(z * D_ + cb + c, kb + c4 * 4)] = *(s16x4*)hi;
    else
      *(s16x4*)&WoH[tiled_off(cb + c, kb + c4 * 4)] = *(s16x4*)hi;
  }
}

// freduce: F4[j][d] = sum of 64 e-chunk partials (fixed order).
__global__ __launch_bounds__(256) void freduce(
    const float* __restrict__ F4p, float* __restrict__ F4)
{
  const int i = blockIdx.x * 256 + threadIdx.x;   // 0..4095
  float s = 0.f;
  #pragma unroll
  for (int eb = 0; eb < 64; eb++) s += F4p[(long)eb * 4096 + i];
  F4[i] = s;
}

// =====================================================================
// Gate-path prep B: H5[d][j] = Wiq[d]·F4[j] (j<4); H5[d][4]=Wiq[d]·bik.
// Consts row H5[1024][j] = F4[j]·biq (j<4), H5[1024][4] = biq·bik.
// One block per d-row (1024 + 1 consts): coalesced 4KB row reads.
// =====================================================================
__global__ __launch_bounds__(256) void hprep2(
    const float* __restrict__ Wiq, const float* __restrict__ F4,
    const float* __restrict__ bik, const float* __restrict__ biq,
    float* __restrict__ H5)
{
  __shared__ float red[4][5];
  const int t = threadIdx.x;
  const int blk = blockIdx.x;
  float s[5] = {0.f, 0.f, 0.f, 0.f, 0.f};
  const float* vr = (blk < 1024) ? Wiq + (long)blk * D_ : biq;
  for (int e = t; e < D_; e += 256) {
    const float w = vr[e];
    s[0] = fmaf(w, F4[e], s[0]);
    s[1] = fmaf(w, F4[D_ + e], s[1]);
    s[2] = fmaf(w, F4[2 * D_ + e], s[2]);
    s[3] = fmaf(w, F4[3 * D_ + e], s[3]);
    s[4] = fmaf(w, bik[e], s[4]);
  }
  #pragma unroll
  for (int j = 0; j < 5; j++)
    #pragma unroll
    for (int m = 1; m < 64; m <<= 1) s[j] += __shfl_xor(s[j], m);
  const int w64 = t >> 6, lane = t & 63;
  if (lane == 0)
    #pragma unroll
    for (int j = 0; j < 5; j++) red[w64][j] = s[j];
  __syncthreads();
  if (t < 5)
    H5[(long)blk * 5 + t] = red[0][t] + red[1][t] + red[2][t] + red[3][t];
}

// =====================================================================
// MFMA GEMM (QKV fused). Tiled bf16 operands, linear global_load_lds
// staging, double-buffered LDS, counted vmcnt(4), XCD-swizzled blocks.
// Plain bf16 (1 MFMA/pair); waves 0,1 stage A halves, waves 2,3 stage
// B halves. 32 KB LDS.
//   z=0: Q-RMSNorm (+qnw, +folded 0.18033688 softmax scale) -> Qnb.
//   z=1: K-RMSNorm fused -> Knb bf16 swizzled.
//   z=2: V -> Vtb bf16 transposed+swizzled.
// =====================================================================
__global__ __launch_bounds__(256) void mfgemmQKV(
    const short* __restrict__ Ahi, const short* __restrict__ Bhi,
    const float* __restrict__ b0, const float* __restrict__ b1,
    const float* __restrict__ b2,
    short* __restrict__ Qout, short* __restrict__ Kout,
    short* __restrict__ Vout,
    const float* __restrict__ qnw, const float* __restrict__ knw)
{
  __shared__ short lds[2][2][4096];
  const int t = threadIdx.x, w = t >> 6, lane = t & 63;
  int bx, by, bz;
  xcd_swizzle(bx, by, bz);
  const int rowBase = by * 128;
  const int colBase = bx * 128;
  const long aoff = (long)by * 131072;   // 128 oct * 128 rows * 8
  const long boff = (long)(bz * 8 + bx) * 131072;

  const int op = w >> 1, half = w & 1;
  const short* mySrc = op ? Bhi + boff : Ahi + aoff;

  auto stage = [&](int buf, int tt) {
    const short* g = mySrc + ((long)tt * 512 + half * 256 + lane) * 8;
    #pragma unroll
    for (int i = 0; i < 4; i++)
      GLOAD16(g + i * 512, &lds[buf][op][(half * 256 + i * 64) * 8]);
  };

  const int wr = w >> 1, wc = w & 1;
  const int lrow = lane & 31, lk = lane >> 5;

  f32x16 acc[2][2] = {};

  auto compute = [&](int buf) {
    #pragma unroll
    for (int kh = 0; kh < 2; kh++) {
      const int kq = 2 * kh + lk;
      bf16x8 ah[2], bh[2];
      #pragma unroll
      for (int m = 0; m < 2; m++)
        ah[m] = *(const bf16x8*)&lds[buf][0][(kq * 128 + wr * 64 + m * 32 + lrow) * 8];
      #pragma unroll
      for (int n = 0; n < 2; n++)
        bh[n] = *(const bf16x8*)&lds[buf][1][(kq * 128 + wc * 64 + n * 32 + lrow) * 8];
      #pragma unroll
      for (int m = 0; m < 2; m++)
        #pragma unroll
        for (int n = 0; n < 2; n++)
          acc[m][n] = mfma_bf16(ah[m], bh[n], acc[m][n]);
    }
  };

  const int NT = 32;   // K=1024 / BK=32
  stage(0, 0);
  for (int tt = 0; tt < NT - 1; ++tt) {
    stage((tt + 1) & 1, tt + 1);
    asm volatile("s_waitcnt vmcnt(4)" ::: "memory");
    __builtin_amdgcn_s_barrier();
    __builtin_amdgcn_sched_barrier(0);
    compute(tt & 1);
    __builtin_amdgcn_s_barrier();
  }
  asm volatile("s_waitcnt vmcnt(0)" ::: "memory");
  __builtin_amdgcn_s_barrier();
  __builtin_amdgcn_sched_barrier(0);
  compute((NT - 1) & 1);

  // ---------------- epilogue ----------------
  const float* bias = (bz == 1) ? b1 : (bz == 2) ? b2 : b0;
  float bcol[2];
  #pragma unroll
  for (int n = 0; n < 2; n++)
    bcol[n] = bias[colBase + wc * 64 + n * 32 + lrow];

  if (bz == 0) {
    // Q plane: RMSNorm (+qnw, +0.18033688 folded scale) -> Qnb bf16.
    const float qw0 = qnw[lrow];
    const float qw1 = qnw[32 + lrow];
    const int col0 = colBase + wc * 64 + lrow;
    #pragma unroll
    for (int m = 0; m < 2; m++)
      #pragma unroll
      for (int r = 0; r < 16; r++) {
        const int row = rowBase + wr * 64 + m * 32 + (r & 3) + 8 * (r >> 2) + 4 * lk;
        const float v0 = acc[m][0][r] + bcol[0];
        const float v1 = acc[m][1][r] + bcol[1];
        float ss = v0 * v0 + v1 * v1;
        ss += __shfl_xor(ss, 1);
        ss += __shfl_xor(ss, 2);
        ss += __shfl_xor(ss, 4);
        ss += __shfl_xor(ss, 8);
        ss += __shfl_xor(ss, 16);
        const float qr = rsqrtf(ss * (1.f / 64.f) + 1e-6f) * 0.1803368801111244f;
        Qout[(long)row * D_ + col0]      = bf16_rn(v0 * qr * qw0);
        Qout[(long)row * D_ + col0 + 32] = bf16_rn(v1 * qr * qw1);
      }
    return;
  }

  if (bz == 1) {
    // K plane: RMSNorm (+knw) -> swizzled Knb (r21-proven).
    const float kw0 = knw[lrow];
    const float kw1 = knw[32 + lrow];
    const int h = (colBase + wc * 64) >> 6;
    #pragma unroll
    for (int m = 0; m < 2; m++)
      #pragma unroll
      for (int r = 0; r < 16; r++) {
        const int row = rowBase + wr * 64 + m * 32 + (r & 3) + 8 * (r >> 2) + 4 * lk;
        const int bb = row >> 9, g = bb >> 2;
        const int mkv = (bb & 3) * 512 + (row & 511);
        const float v0 = acc[m][0][r] + bcol[0];
        const float v1 = acc[m][1][r] + bcol[1];
        float ks2 = v0 * v0 + v1 * v1;
        ks2 += __shfl_xor(ks2, 1);
        ks2 += __shfl_xor(ks2, 2);
        ks2 += __shfl_xor(ks2, 4);
        ks2 += __shfl_xor(ks2, 8);
        ks2 += __shfl_xor(ks2, 16);
        const float kr = rsqrtf(ks2 * (1.f / 64.f) + 1e-6f);
        const long base = ((long)(g * H_ + h) * KVLEN + mkv) * 64;
        const int d0 = lrow, d1 = 32 + lrow;
        Kout[base + (((d0 >> 3) ^ (mkv & 7)) << 3) + (d0 & 7)] = bf16_rn(v0 * kr * kw0);
        Kout[base + (((d1 >> 3) ^ (mkv & 7)) << 3) + (d1 & 7)] = bf16_rn(v1 * kr * kw1);
      }
    return;
  }

  // V plane: write straight to Vtb [g][h][tile][d][32kv] swizzled.
  #pragma unroll
  for (int m = 0; m < 2; m++)
    #pragma unroll
    for (int r = 0; r < 16; r++) {
      const int row = rowBase + wr * 64 + m * 32 + (r & 3) + 8 * (r >> 2) + 4 * lk;
      const int bb = row >> 9, g = bb >> 2;
      const int kv = (bb & 3) * 512 + (row & 511);
      const int tile = kv >> 5, vkv = kv & 31;
      #pragma unroll
      for (int n = 0; n < 2; n++) {
        const int col = colBase + wc * 64 + n * 32 + lrow;
        const int h = col >> 6, dl = col & 63;
        const long idx = ((long)(g * H_ + h) * 64 + tile) * 2048
                       + dl * 32 + (((vkv >> 3) ^ ((dl >> 1) & 3)) * 8) + (vkv & 7);
        Vout[idx] = bf16_rn(acc[m][n][r] + bcol[n]);
      }
    }
}

// =====================================================================
// mfgemmF — FINAL GEMM, 128x64 tiles (r24): grid (16,32) = 512 blocks
// = 2 blocks/CU (the r9 lesson: 1 block/CU GEMMs are latency-bound with
// zero inter-block overlap; 18us at 480 TF). Waves 0,1 stage A halves
// (4 gloads each); wave 2 stages the 64-col B slab (4 x 1KB contiguous
// gloads — a 64-row half of a 128-row tile-block is 1KB contiguous per
// k-octet); wave 3 idles (proven pattern). 24 KB LDS, uniform vmcnt(4).
// Per-element K-accumulation order identical -> bit-identical output.
// out[row,col] = gate[row]*(o@Wo)[row,col] + bo[col].
// =====================================================================
__global__ __launch_bounds__(256) void mfgemmF(
    const short* __restrict__ Ahi, const short* __restrict__ Bhi,
    const float* __restrict__ bo, float* __restrict__ C,
    const float* __restrict__ gate_in)
{
  __shared__ short As[2][4096];   // [kq 4][row 128][8]
  __shared__ short Bs[2][2048];   // [kq 4][col 64][8]
  const int t = threadIdx.x, w = t >> 6, lane = t & 63;
  int bx, by, bz;
  xcd_swizzle(bx, by, bz);
  const int rowBase = by * 128;
  const int colBase = bx * 64;
  const long aoff = (long)by * 131072;

  auto stage = [&](int buf, int tt) {
    if (w < 2) {
      const short* g = Ahi + aoff + ((long)tt * 512 + w * 256 + lane) * 8;
      #pragma unroll
      for (int i = 0; i < 4; i++)
        GLOAD16(g + i * 512, &As[buf][(w * 256 + i * 64) * 8]);
    } else if (w == 2) {
      const short* g = Bhi + ((long)(bx >> 1) * 128 + (long)tt * 4) * 1024
                     + (bx & 1) * 512 + lane * 8;
      #pragma unroll
      for (int i = 0; i < 4; i++)
        GLOAD16(g + i * 1024, &Bs[buf][i * 512]);
    }
  };

  const int wr = w >> 1, wc = w & 1;
  const int lrow = lane & 31, lk = lane >> 5;

  f32x16 acc[2] = {};

  auto compute = [&](int buf) {
    #pragma unroll
    for (int kh = 0; kh < 2; kh++) {
      const int kq = 2 * kh + lk;
      bf16x8 bh = *(const bf16x8*)&Bs[buf][(kq * 64 + wc * 32 + lrow) * 8];
      #pragma unroll
      for (int m = 0; m < 2; m++) {
        bf16x8 ah = *(const bf16x8*)&As[buf][(kq * 128 + wr * 64 + m * 32 + lrow) * 8];
        acc[m] = mfma_bf16(ah, bh, acc[m]);
      }
    }
  };

  const int NT = 32;
  stage(0, 0);
  for (int tt = 0; tt < NT - 1; ++tt) {
    stage((tt + 1) & 1, tt + 1);
    asm volatile("s_waitcnt vmcnt(4)" ::: "memory");
    __builtin_amdgcn_s_barrier();
    __builtin_amdgcn_sched_barrier(0);
    compute(tt & 1);
    __builtin_amdgcn_s_barrier();
  }
  asm volatile("s_waitcnt vmcnt(0)" ::: "memory");
  __builtin_amdgcn_s_barrier();
  __builtin_amdgcn_sched_barrier(0);
  compute((NT - 1) & 1);

  // ---------------- epilogue: gate + bias ----------------
  const int col = colBase + wc * 32 + lrow;
  const float bc = bo[col];
  #pragma unroll
  for (int m = 0; m < 2; m++)
    #pragma unroll
    for (int r = 0; r < 16; r++) {
      const int row = rowBase + wr * 64 + m * 32 + (r & 3) + 8 * (r >> 2) + 4 * lk;
      C[(long)row * D_ + col] = acc[m][r] * gate_in[row] + bc;
    }
}

// =====================================================================
// MFMA grouped flash attention — KV-SPLIT x2, KVBLK=64, XCD-swizzled.
// Q pre-normalized/pre-scaled bf16; tree-summed l; bf16 o partials.
// STATIC max: partials combine exactly (o=sum, l=sum). (r23-proven)
// =====================================================================
__global__ __launch_bounds__(256) void attn3(
    const short* __restrict__ q, const short* __restrict__ Knb,
    const short* __restrict__ Vtb,
    short* __restrict__ opart, float* __restrict__ lpart)
{
  int qb, h, bz;
  xcd_swizzle(qb, h, bz);
  const int b  = bz >> 1, s = bz & 1;
  const int g  = b >> 2;
  const int t  = threadIdx.x;
  const int w  = t >> 6;
  const int lane = t & 63;
  const int l31 = lane & 31, hi = lane >> 5;

  __shared__ short Kt[2][4096];
  __shared__ short Vt[2][4096];

  // ---- Q fragments: direct bf16 loads (pre-normalized, pre-scaled) ----
  const int qrow = qb * 128 + w * 32 + l31;
  const short* qp = q + ((long)b * N_ + qrow) * D_ + h * HD_ + hi * 8;
  bf16x8 qf[4];
  #pragma unroll
  for (int c = 0; c < 4; c++)
    qf[c] = *(const bf16x8*)&qp[c * 16];

  const short* Kg = Knb + (long)(g * H_ + h) * KVLEN * 64 + (long)s * 32 * 2048;
  const short* Vg = Vtb + (long)(g * H_ + h) * 64 * 2048 + (long)s * 32 * 2048;

  auto stage = [&](int buf, int i) {   // i = 64-kv chunk, 0..15
    GLOAD16(Kg + (long)i * 4096 + t * 8,        &Kt[buf][w * 512]);
    GLOAD16(Kg + (long)i * 4096 + 2048 + t * 8, &Kt[buf][2048 + w * 512]);
    GLOAD16(Vg + (long)i * 4096 + t * 8,        &Vt[buf][w * 512]);
    GLOAD16(Vg + (long)i * 4096 + 2048 + t * 8, &Vt[buf][2048 + w * 512]);
  };

  f32x16 oacc[2] = {};
  float l = 0.f;

  stage(0, 0);
  for (int i = 0; i < 16; ++i) {
    const int buf = i & 1;
    if (i + 1 < 16) {
      stage(buf ^ 1, i + 1);
      asm volatile("s_waitcnt vmcnt(4)" ::: "memory");
    } else {
      asm volatile("s_waitcnt vmcnt(0)" ::: "memory");
    }
    __builtin_amdgcn_s_barrier();
    __builtin_amdgcn_sched_barrier(0);

    #pragma unroll
    for (int ss = 0; ss < 2; ss++) {
      const short* Ktb = &Kt[buf][ss * 2048];
      const short* Vsb = &Vt[buf][ss * 2048];
      // ---- QK^T: scores[kv][q], pre-scaled via folded Q scale ----
      f32x16 sc = {};
      #pragma unroll
      for (int c = 0; c < 4; c++) {
        bf16x8 kfr = *(const bf16x8*)&Ktb[l31 * 64 + (((2 * c + hi) * 8) ^ ((l31 & 7) << 3))];
        sc = mfma_bf16(kfr, qf[c], sc);
      }
      // ---- softmax kernel: p~ = exp2(sc); l via balanced tree ----
      float p[16];
      #pragma unroll
      for (int r = 0; r < 16; r++)
        p[r] = exp2f(sc[r]);
      l += ((((p[0] + p[1]) + (p[2] + p[3])) + ((p[4] + p[5]) + (p[6] + p[7])))
         + (((p[8] + p[9]) + (p[10] + p[11])) + ((p[12] + p[13]) + (p[14] + p[15]))));
      // ---- pack P pairs to bf16 (cvt_pk), half-swap via permlane32 ----
      unsigned wd[8];
      #pragma unroll
      for (int i2 = 0; i2 < 8; i2++)
        asm("v_cvt_pk_bf16_f32 %0, %1, %2" : "=v"(wd[i2]) : "v"(p[2 * i2]), "v"(p[2 * i2 + 1]));
      u32x2 r0 = __builtin_amdgcn_permlane32_swap(wd[0], wd[2], false, false);
      u32x2 r1 = __builtin_amdgcn_permlane32_swap(wd[1], wd[3], false, false);
      u32x2 r2 = __builtin_amdgcn_permlane32_swap(wd[4], wd[6], false, false);
      u32x2 r3 = __builtin_amdgcn_permlane32_swap(wd[5], wd[7], false, false);
      int4 f0 = { (int)r0.x, (int)r1.x, (int)r0.y, (int)r1.y };
      int4 f1 = { (int)r2.x, (int)r3.x, (int)r2.y, (int)r3.y };
      // ---- PV ----
      #pragma unroll
      for (int n = 0; n < 2; n++) {
        const int d = n * 32 + l31;
        const int fd = (d >> 1) & 3;
        bf16x8 v0 = *(const bf16x8*)&Vsb[d * 32 + ((hi ^ fd) * 8)];
        bf16x8 v1 = *(const bf16x8*)&Vsb[d * 32 + (((2 | hi) ^ fd) * 8)];
        oacc[n] = mfma_bf16(__builtin_bit_cast(bf16x8, f0), v0, oacc[n]);
        oacc[n] = mfma_bf16(__builtin_bit_cast(bf16x8, f1), v1, oacc[n]);
      }
    }
    __builtin_amdgcn_s_barrier();
  }

  // ---- epilogue: write PARTIAL o (bf16, no divide) + l, plane s ----
  l += __shfl_xor(l, 32);
  #pragma unroll
  for (int r = 0; r < 16; r++) {
    const int qg = qb * 128 + w * 32 + (r & 3) + 8 * (r >> 2) + 4 * hi;
    short* op = opart + ((long)s * BN_ + b * N_ + qg) * D_ + h * HD_ + l31;
    op[0]  = bf16_rn(oacc[0][r]);
    op[32] = bf16_rn(oacc[1][r]);
  }
  if (hi == 0)
    lpart[((long)s * BN_ + b * N_ + qb * 128 + w * 32 + l31) * H_ + h] = l;
}

// =====================================================================
// attn_reduce2 — FUSED reduce + gate (bf16 partials; o hi-only).
//  A: o = (o0+o1)/(l0+l1) -> tiled bf16
//  B: G[0:5] = o·H5[:,j] + H5[1024][j]  (block reduce; G never stored)
//  C: gate[row] = 1 + mean_m sigmoid(sc*(G·mask[b][m] + G4))
// =====================================================================
__global__ __launch_bounds__(256) void attn_reduce2(
    const short* __restrict__ opart, const float* __restrict__ lpart,
    const float* __restrict__ H5, const float* __restrict__ mask,
    short* __restrict__ ohi, float* __restrict__ gate)
{
  __shared__ float red[4][5];
  __shared__ float Gs[5];
  __shared__ float sred[4];
  const int t = threadIdx.x;
  const int row = blockIdx.x;
  const int bb = row >> 9;
  const int col = t * 4;
  const int h   = col >> 6;
  // ---- A: combine 2 bf16 partial planes ----
  const float l = lpart[(long)row * H_ + h] + lpart[((long)BN_ + row) * H_ + h];
  const float inv = 1.f / l;
  s16x4 a4 = *(const s16x4*)&opart[(long)row * D_ + col];
  s16x4 b4 = *(const s16x4*)&opart[((long)BN_ + row) * D_ + col];
  float o4[4];
  #pragma unroll
  for (int c = 0; c < 4; c++)
    o4[c] = (bf2f(a4[c]) + bf2f(b4[c])) * inv;
  short hh[4];
  hh[0] = bf16_rn(o4[0]);  hh[1] = bf16_rn(o4[1]);
  hh[2] = bf16_rn(o4[2]);  hh[3] = bf16_rn(o4[3]);
  *(s16x4*)&ohi[tiled_off(row, col)] = *(s16x4*)hh;
  // ---- B: G = o . H5 (block reduce) ----
  float s[5] = {0.f, 0.f, 0.f, 0.f, 0.f};
  #pragma unroll
  for (int cc = 0; cc < 4; cc++) {
    const float* hp = &H5[(long)(col + cc) * 5];
    #pragma unroll
    for (int j = 0; j < 5; j++) s[j] = fmaf(o4[cc], hp[j], s[j]);
  }
  #pragma unroll
  for (int j = 0; j < 5; j++)
    #pragma unroll
    for (int m = 1; m < 64; m <<= 1) s[j] += __shfl_xor(s[j], m);
  const int w64 = t >> 6, lane = t & 63;
  if (lane == 0)
    #pragma unroll
    for (int j = 0; j < 5; j++) red[w64][j] = s[j];
  __syncthreads();
  if (t < 5) Gs[t] = red[0][t] + red[1][t] + red[2][t] + red[3][t] + H5[5120 + t];
  __syncthreads();
  const float g0 = Gs[0], g1 = Gs[1], g2 = Gs[2], g3 = Gs[3], g4 = Gs[4];
  // ---- C: gate via 512 sigmoids spread over the block ----
  const float sc = 0.125f / 16.f;       // SCALE/H
  const float* mrow = mask + (long)bb * N_ * NI_;
  float sg = 0.f;
  #pragma unroll
  for (int q = 0; q < 2; q++) {
    const float4 mk = *(const float4*)&mrow[(t * 2 + q) * 4];
    const float z = fmaf(g0, mk.x, fmaf(g1, mk.y, fmaf(g2, mk.z, fmaf(g3, mk.w, g4))));
    sg += 1.f / (1.f + __expf(-z * sc));
  }
  #pragma unroll
  for (int m = 1; m < 64; m <<= 1) sg += __shfl_xor(sg, m);
  if (lane == 0) sred[w64] = sg;
  __syncthreads();
  if (t == 0)
    gate[row] = 1.f + (sred[0] + sred[1] + sred[2] + sred[3]) * (1.f / 512.f);
}

// =====================================================================
extern "C" void kernel_launch(void* const* d_in, const int* in_sizes, int n_in,
                              void* d_out, int out_size, void* d_ws, size_t ws_size,
                              hipStream_t stream)
{
  const float* x    = (const float*)d_in[0];
  const float* mask = (const float*)d_in[1];
  const float* Wq   = (const float*)d_in[2];
  const float* bq   = (const float*)d_in[3];
  const float* Wk   = (const float*)d_in[4];
  const float* bk   = (const float*)d_in[5];
  const float* Wv   = (const float*)d_in[6];
  const float* bv   = (const float*)d_in[7];
  const float* Wo   = (const float*)d_in[8];
  const float* bo   = (const float*)d_in[9];
  const float* Wiq  = (const float*)d_in[10];
  const float* biq  = (const float*)d_in[11];
  const float* Wik  = (const float*)d_in[12];
  const float* bik  = (const float*)d_in[13];
  const float* emb  = (const float*)d_in[14];
  const float* qnw  = (const float*)d_in[15];
  const float* knw  = (const float*)d_in[16];
  float* out = (float*)d_out;

  // Workspace (within the round-9-proven footprint).
  // Lifetime audit (launch #):
  //  [0,SZ)     Qnb bf16 (w:4(QKV z=0 epi) r:5) -> ohi bf16 (w:6 r:7)
  //  [SZ,2SZ)   opart bf16 [2][BN][D] shorts (w:5 r:6). Dead during QKV.
  //  [3SZ,4SZ)  Knb bf16 (w:4(QKV z=1 epi) r:5). Dead during staging.
  //  [4SZ,4.5SZ) xhi: x tiled bf16 (w:1 r:4)
  //  [4.5SZ,5SZ) Vtb bf16 (w:4(QKV z=2 epi) r:5) — overlays dead xlo
  //  Wbig_hi:   QKV weights (w:1 r:4) -> gate + lpart[2] (w:6/5 r:7/6)
  //  Wbig_lo:   WoH (w:1 r:7) | F4 (w:2 r:3) | H5 (w:3 r:6) | F4p (w:1 r:2)
  float* ws = (float*)d_ws;
  const size_t SZ = (size_t)BN_ * D_;
  short* Qnb  = (short*)ws;             // [BN][1024] bf16 (normalized q)
  short* ohi  = (short*)ws;             // post-attn3: o bf16 tiled
  short* opart = (short*)(ws + SZ);     // [2][BN][D] bf16 attn partials
  short* Knb  = (short*)(ws + 3 * SZ);  // [2][16][2048][64] bf16
  short* xhi  = (short*)(ws + 4 * SZ);
  short* Vtb  = xhi + SZ;               // [2][16][64][64][32] bf16
  short* Wbig_hi = (short*)(ws + 5 * SZ);
  short* Wbig_lo = Wbig_hi + (size_t)3 * D_ * D_;
  float* gate  = (float*)Wbig_hi;                       // [BN] (post-QKV)
  float* lpart = gate + BN_;                            // [2][BN][16]
  short* WoH = Wbig_lo;                                 // [D][D] tiled
  float* F4  = (float*)(Wbig_lo + (size_t)D_ * D_);     // [4][1024]
  float* H5  = F4 + 4 * D_;                             // [1025][5]
  float* F4p = H5 + 1025 * 5;                           // [64][4][1024]

  const dim3 blk(256);

  // 1) weight prep + x convert + gate-prep-A, ONE dispatch (z=0..8)
  wsplitAll<<<dim3(16, 16, 9), blk, 0, stream>>>(
      Wq, Wk, Wv, Wo, x, Wik, emb, Wbig_hi, WoH, xhi, F4p);

  // 2-3) gate-path algebra prep (rank-5 collapse)
  freduce<<<dim3(16), blk, 0, stream>>>(F4p, F4);
  hprep2<<<dim3(1025), blk, 0, stream>>>(Wiq, F4, bik, biq, H5);

  // 4) fused QKV projection; Q-norm -> Qnb, K-norm -> Knb, V -> Vtb
  mfgemmQKV<<<dim3(8, 32, 3), blk, 0, stream>>>(
      xhi, Wbig_hi, bq, bk, bv, Qnb, Knb, Vtb, qnw, knw);

  // 5) attention, KV-split x2, KVBLK=64 -> bf16 partials
  attn3<<<dim3(N_ / 128, H_, B_ * 2), blk, 0, stream>>>(
      Qnb, Knb, Vtb, opart, lpart);

  // 6) combine partials -> o bf16 (over dead Qnb region), gate in-block
  attn_reduce2<<<BN_, blk, 0, stream>>>(opart, lpart, H5, mask, ohi, gate);

  // 7) final: gate[row]*(o@Wo) + bo -> d_out (128x64 tiles, 2 blocks/CU)
  mfgemmF<<<dim3(16, 32), blk, 0, stream>>>(ohi, WoH, bo, out, gate);
}

// Round 25
// 174.639 us; speedup vs baseline: 1.0028x; 1.0028x over previous
//
#include <hip/hip_runtime.h>
#include <cmath>

// Problem constants (fixed by the reference file)
#define B_   8
#define N_   512
#define D_   1024
#define H_   16
#define HD_  64
#define NI_  4
#define BN_  (B_*N_)      // 4096 rows when [B,N,*] is flattened
#define KVLEN (NI_*N_)    // 2048 keys per attention group

typedef __attribute__((ext_vector_type(8)))  short  bf16x8;   // 8 bf16 bit patterns
typedef __attribute__((ext_vector_type(8)))  __bf16 bf16x8_t; // builtin operand type
typedef __attribute__((ext_vector_type(16))) float  f32x16;
typedef __attribute__((ext_vector_type(4)))  short  s16x4;
typedef __attribute__((ext_vector_type(2)))  unsigned u32x2;

// round-to-nearest-even bf16 conversion (bit trick)
__device__ __forceinline__ short bf16_rn(float x) {
  unsigned u = __float_as_uint(x);
  unsigned r = (u + 0x7FFFu + ((u >> 16) & 1u)) >> 16;
  return (short)r;
}

__device__ __forceinline__ float bf2f(short x) {
  return __uint_as_float(((unsigned)(unsigned short)x) << 16);
}

__device__ __forceinline__ f32x16 mfma_bf16(bf16x8 a, bf16x8 b, f32x16 c) {
  return __builtin_amdgcn_mfma_f32_32x32x16_bf16(
      __builtin_bit_cast(bf16x8_t, a), __builtin_bit_cast(bf16x8_t, b), c, 0, 0, 0);
}

#define GLOAD16(gp, lp) __builtin_amdgcn_global_load_lds( \
  (const __attribute__((address_space(1))) unsigned*)(gp), \
  (__attribute__((address_space(3))) unsigned*)(lp), 16, 0, 0)

// TILED layout for all bf16 GEMM operands (K = 1024):
// addr(row,k) = (((row>>7)*128 + (k>>3))*128 + (row&127))*8 + (k&7).
// GEMM staging is then a LINEAR copy -> fully coalesced global_load_lds.
__device__ __forceinline__ long tiled_off(int row, int k) {
  return ((((long)(row >> 7) * 128 + (k >> 3)) * 128 + (row & 127)) * 8 + (k & 7));
}

// T1 XCD-aware block swizzle (MI355X: 8 XCDs, private L2s). Remap so each
// XCD gets a CONTIGUOUS tile range. REQUIRES nwg % 8 == 0.
__device__ __forceinline__ void xcd_swizzle(int& bx, int& by, int& bz) {
  const int gx = gridDim.x, gy = gridDim.y;
  const int nwg = gx * gy * gridDim.z;
  const int lin = blockIdx.x + gx * (blockIdx.y + gy * blockIdx.z);
  const int swz = (lin & 7) * (nwg >> 3) + (lin >> 3);
  bx = swz % gx;
  const int rest = swz / gx;
  by = rest % gy;
  bz = rest / gy;
}

// =====================================================================
// Weight + x prep, ONE dispatch (z=0..7):
//  z=0..2: Wq/Wk/Wv -> QKVh (combined [3072][1024] tiled, transposed)
//  z=3:    Wo -> WoH (tiled, transposed)
//  z=4..7: x rows (z-4)*1024.. -> Xh (tiled, direct convert)
// All hi-only bf16.
// =====================================================================
__global__ __launch_bounds__(256) void wsplitAll(
    const float* __restrict__ Wq, const float* __restrict__ Wk,
    const float* __restrict__ Wv, const float* __restrict__ Wo,
    const float* __restrict__ x,
    short* __restrict__ QKVh, short* __restrict__ WoH,
    short* __restrict__ Xh)
{
  const int z = blockIdx.z;
  const int t  = threadIdx.x;
  if (z >= 4) {
    const int rowB = (z - 4) * 1024 + blockIdx.y * 64;
    const int colB = blockIdx.x * 64;
    const int r0 = t >> 4;
    const int c4 = t & 15;
    #pragma unroll
    for (int i = 0; i < 4; i++) {
      const int row = rowB + r0 + i * 16;
      float4 v = *(const float4*)&x[(long)row * D_ + colB + c4 * 4];
      short h[4];
      h[0] = bf16_rn(v.x);  h[1] = bf16_rn(v.y);
      h[2] = bf16_rn(v.z);  h[3] = bf16_rn(v.w);
      *(s16x4*)&Xh[tiled_off(row, colB + c4 * 4)] = *(s16x4*)h;
    }
    return;
  }
  __shared__ float tile[64][65];
  const float* W = (z == 0) ? Wq : (z == 1) ? Wk : (z == 2) ? Wv : Wo;
  const int kb = blockIdx.y * 64;
  const int cb = blockIdx.x * 64;
  const int r0 = t >> 4;
  const int c4 = t & 15;
  #pragma unroll
  for (int i = 0; i < 4; i++) {
    const int r = r0 + i * 16;
    *(float4*)&tile[r][c4 * 4] = *(const float4*)&W[(long)(kb + r) * D_ + cb + c4 * 4];
  }
  __syncthreads();
  #pragma unroll
  for (int i = 0; i < 4; i++) {
    const int c = r0 + i * 16;
    short hi[4];
    #pragma unroll
    for (int e = 0; e < 4; e++)
      hi[e] = bf16_rn(tile[c4 * 4 + e][c]);
    if (z < 3)
      *(s16x4*)&QKVh[tiled_off(z * D_ + cb + c, kb + c4 * 4)] = *(s16x4*)hi;
    else
      *(s16x4*)&WoH[tiled_off(cb + c, kb + c4 * 4)] = *(s16x4*)hi;
  }
}

// =====================================================================
// Gate-path prep A: F4p[eb][j][d] = sum_{e in 16-chunk eb} emb[j][e] *
// Wik[e][d].  grid (4,64) = 256 blocks; coalesced 1KB row segments.
// =====================================================================
__global__ __launch_bounds__(256) void fprep_p(
    const float* __restrict__ Wik, const float* __restrict__ emb,
    float* __restrict__ F4p)
{
  const int d  = blockIdx.x * 256 + threadIdx.x;
  const int eb = blockIdx.y;
  float s0 = 0, s1 = 0, s2 = 0, s3 = 0;
  for (int e = eb * 16; e < eb * 16 + 16; e++) {
    const float w = Wik[(long)e * D_ + d];
    s0 = fmaf(emb[e], w, s0);
    s1 = fmaf(emb[D_ + e], w, s1);
    s2 = fmaf(emb[2 * D_ + e], w, s2);
    s3 = fmaf(emb[3 * D_ + e], w, s3);
  }
  float* p = F4p + (long)eb * 4 * D_;
  p[d] = s0;  p[D_ + d] = s1;  p[2 * D_ + d] = s2;  p[3 * D_ + d] = s3;
}

// freduce: F4[j][d] = sum of 64 e-chunk partials (fixed order).
__global__ __launch_bounds__(256) void freduce(
    const float* __restrict__ F4p, float* __restrict__ F4)
{
  const int i = blockIdx.x * 256 + threadIdx.x;   // 0..4095
  float s = 0.f;
  #pragma unroll
  for (int eb = 0; eb < 64; eb++) s += F4p[(long)eb * 4096 + i];
  F4[i] = s;
}

// =====================================================================
// Gate-path prep B: H5[d][j] = Wiq[d]·F4[j] (j<4); H5[d][4]=Wiq[d]·bik.
// Consts row H5[1024][j] = F4[j]·biq (j<4), H5[1024][4] = biq·bik.
// One block per d-row (1024 + 1 consts): coalesced 4KB row reads.
// =====================================================================
__global__ __launch_bounds__(256) void hprep2(
    const float* __restrict__ Wiq, const float* __restrict__ F4,
    const float* __restrict__ bik, const float* __restrict__ biq,
    float* __restrict__ H5)
{
  __shared__ float red[4][5];
  const int t = threadIdx.x;
  const int blk = blockIdx.x;
  float s[5] = {0.f, 0.f, 0.f, 0.f, 0.f};
  const float* vr = (blk < 1024) ? Wiq + (long)blk * D_ : biq;
  for (int e = t; e < D_; e += 256) {
    const float w = vr[e];
    s[0] = fmaf(w, F4[e], s[0]);
    s[1] = fmaf(w, F4[D_ + e], s[1]);
    s[2] = fmaf(w, F4[2 * D_ + e], s[2]);
    s[3] = fmaf(w, F4[3 * D_ + e], s[3]);
    s[4] = fmaf(w, bik[e], s[4]);
  }
  #pragma unroll
  for (int j = 0; j < 5; j++)
    #pragma unroll
    for (int m = 1; m < 64; m <<= 1) s[j] += __shfl_xor(s[j], m);
  const int w64 = t >> 6, lane = t & 63;
  if (lane == 0)
    #pragma unroll
    for (int j = 0; j < 5; j++) red[w64][j] = s[j];
  __syncthreads();
  if (t < 5)
    H5[(long)blk * 5 + t] = red[0][t] + red[1][t] + red[2][t] + red[3][t];
}

// =====================================================================
// MFMA GEMM v10. Tiled bf16 operands, linear global_load_lds staging,
// double-buffered LDS, counted vmcnt(4), XCD-swizzled blocks.
// Plain bf16 (1 MFMA/pair); waves 0,1 stage A halves, waves 2,3 stage
// B halves. 32 KB LDS.
// MODE 6: QKV fused.
//   z=0: Q-RMSNorm (+qnw, +folded 0.18033688 softmax scale) -> Qnb.
//   z=1: K-RMSNorm fused -> Knb bf16 swizzled.
//   z=2: V -> Vtb bf16 transposed+swizzled.
// MODE 2: C = gate[row]*(A@B) + bias                  (final)
// =====================================================================
template<int MODE>
__global__ __launch_bounds__(256) void mfgemm2(
    const short* __restrict__ Ahi, const short* __restrict__ Bhi,
    const float* __restrict__ b0, const float* __restrict__ b1,
    const float* __restrict__ b2,
    float* __restrict__ C, short* __restrict__ Qout,
    short* __restrict__ Kout, short* __restrict__ Vout,
    const float* __restrict__ qnw, const float* __restrict__ knw,
    int bBlk, long sC, const float* __restrict__ gate_in)
{
  __shared__ short lds[2][2][4096];
  const int t = threadIdx.x, w = t >> 6, lane = t & 63;
  int bx, by, bz;
  xcd_swizzle(bx, by, bz);
  const int rowBase = by * 128;
  const int colBase = bx * 128;
  const long aoff = (long)by * 131072;   // 128 oct * 128 rows * 8
  const long boff = (long)(bz * bBlk + bx) * 131072;

  const int op = w >> 1, half = w & 1;
  const short* mySrc = op ? Bhi + boff : Ahi + aoff;

  auto stage = [&](int buf, int tt) {
    const short* g = mySrc + ((long)tt * 512 + half * 256 + lane) * 8;
    #pragma unroll
    for (int i = 0; i < 4; i++)
      GLOAD16(g + i * 512, &lds[buf][op][(half * 256 + i * 64) * 8]);
  };

  const int wr = w >> 1, wc = w & 1;
  const int lrow = lane & 31, lk = lane >> 5;

  f32x16 acc[2][2] = {};

  auto compute = [&](int buf) {
    #pragma unroll
    for (int kh = 0; kh < 2; kh++) {
      const int kq = 2 * kh + lk;
      bf16x8 ah[2], bh[2];
      #pragma unroll
      for (int m = 0; m < 2; m++)
        ah[m] = *(const bf16x8*)&lds[buf][0][(kq * 128 + wr * 64 + m * 32 + lrow) * 8];
      #pragma unroll
      for (int n = 0; n < 2; n++)
        bh[n] = *(const bf16x8*)&lds[buf][1][(kq * 128 + wc * 64 + n * 32 + lrow) * 8];
      #pragma unroll
      for (int m = 0; m < 2; m++)
        #pragma unroll
        for (int n = 0; n < 2; n++)
          acc[m][n] = mfma_bf16(ah[m], bh[n], acc[m][n]);
    }
  };

  const int NT = 32;   // K=1024 / BK=32
  stage(0, 0);
  for (int tt = 0; tt < NT - 1; ++tt) {
    stage((tt + 1) & 1, tt + 1);
    asm volatile("s_waitcnt vmcnt(4)" ::: "memory");
    __builtin_amdgcn_s_barrier();
    __builtin_amdgcn_sched_barrier(0);
    compute(tt & 1);
    __builtin_amdgcn_s_barrier();
  }
  asm volatile("s_waitcnt vmcnt(0)" ::: "memory");
  __builtin_amdgcn_s_barrier();
  __builtin_amdgcn_sched_barrier(0);
  compute((NT - 1) & 1);

  // ---------------- epilogue ----------------
  const float* bias = (bz == 1) ? b1 : (bz == 2) ? b2 : b0;
  float bcol[2];
  #pragma unroll
  for (int n = 0; n < 2; n++)
    bcol[n] = bias[colBase + wc * 64 + n * 32 + lrow];

  if (MODE == 6 && bz == 0) {
    // Q plane: RMSNorm (+qnw, +0.18033688 folded scale) -> Qnb bf16.
    const float qw0 = qnw[lrow];
    const float qw1 = qnw[32 + lrow];
    const int col0 = colBase + wc * 64 + lrow;
    #pragma unroll
    for (int m = 0; m < 2; m++)
      #pragma unroll
      for (int r = 0; r < 16; r++) {
        const int row = rowBase + wr * 64 + m * 32 + (r & 3) + 8 * (r >> 2) + 4 * lk;
        const float v0 = acc[m][0][r] + bcol[0];
        const float v1 = acc[m][1][r] + bcol[1];
        float ss = v0 * v0 + v1 * v1;
        ss += __shfl_xor(ss, 1);
        ss += __shfl_xor(ss, 2);
        ss += __shfl_xor(ss, 4);
        ss += __shfl_xor(ss, 8);
        ss += __shfl_xor(ss, 16);
        const float qr = rsqrtf(ss * (1.f / 64.f) + 1e-6f) * 0.1803368801111244f;
        Qout[(long)row * D_ + col0]      = bf16_rn(v0 * qr * qw0);
        Qout[(long)row * D_ + col0 + 32] = bf16_rn(v1 * qr * qw1);
      }
    return;
  }

  if (MODE == 6 && bz == 1) {
    // K plane: RMSNorm (+knw) -> swizzled Knb (r21-proven).
    const float kw0 = knw[lrow];
    const float kw1 = knw[32 + lrow];
    const int h = (colBase + wc * 64) >> 6;
    #pragma unroll
    for (int m = 0; m < 2; m++)
      #pragma unroll
      for (int r = 0; r < 16; r++) {
        const int row = rowBase + wr * 64 + m * 32 + (r & 3) + 8 * (r >> 2) + 4 * lk;
        const int bb = row >> 9, g = bb >> 2;
        const int mkv = (bb & 3) * 512 + (row & 511);
        const float v0 = acc[m][0][r] + bcol[0];
        const float v1 = acc[m][1][r] + bcol[1];
        float ks2 = v0 * v0 + v1 * v1;
        ks2 += __shfl_xor(ks2, 1);
        ks2 += __shfl_xor(ks2, 2);
        ks2 += __shfl_xor(ks2, 4);
        ks2 += __shfl_xor(ks2, 8);
        ks2 += __shfl_xor(ks2, 16);
        const float kr = rsqrtf(ks2 * (1.f / 64.f) + 1e-6f);
        const long base = ((long)(g * H_ + h) * KVLEN + mkv) * 64;
        const int d0 = lrow, d1 = 32 + lrow;
        Kout[base + (((d0 >> 3) ^ (mkv & 7)) << 3) + (d0 & 7)] = bf16_rn(v0 * kr * kw0);
        Kout[base + (((d1 >> 3) ^ (mkv & 7)) << 3) + (d1 & 7)] = bf16_rn(v1 * kr * kw1);
      }
    return;
  }

  if (MODE == 6 && bz == 2) {
    // V plane: write straight to Vtb [g][h][tile][d][32kv] swizzled.
    #pragma unroll
    for (int m = 0; m < 2; m++)
      #pragma unroll
      for (int r = 0; r < 16; r++) {
        const int row = rowBase + wr * 64 + m * 32 + (r & 3) + 8 * (r >> 2) + 4 * lk;
        const int bb = row >> 9, g = bb >> 2;
        const int kv = (bb & 3) * 512 + (row & 511);
        const int tile = kv >> 5, vkv = kv & 31;
        #pragma unroll
        for (int n = 0; n < 2; n++) {
          const int col = colBase + wc * 64 + n * 32 + lrow;
          const int h = col >> 6, dl = col & 63;
          const long idx = ((long)(g * H_ + h) * 64 + tile) * 2048
                         + dl * 32 + (((vkv >> 3) ^ ((dl >> 1) & 3)) * 8) + (vkv & 7);
          Vout[idx] = bf16_rn(acc[m][n][r] + bcol[n]);
        }
      }
    return;
  }

  float* Cb = C + (long)bz * sC;
  #pragma unroll
  for (int m = 0; m < 2; m++) {
    #pragma unroll
    for (int r = 0; r < 16; r++) {
      const int row = rowBase + wr * 64 + m * 32 + (r & 3) + 8 * (r >> 2) + 4 * lk;
      float g = 1.f;
      if (MODE == 2) g = gate_in[row];
      #pragma unroll
      for (int n = 0; n < 2; n++) {
        const int col = colBase + wc * 64 + n * 32 + lrow;
        Cb[(long)row * D_ + col] = acc[m][n][r] * g + bcol[n];
      }
    }
  }
}

// =====================================================================
// MFMA grouped flash attention — KV-SPLIT x2, XCD-swizzled.
// KVBLK=64 — two 32-kv sub-tiles per barrier pair (iterations 32->16,
// barriers halved; per-sub-tile body executes in the same kv order ->
// bit-identical l/oacc accumulation). LDS 32 KB. 4 gloads/stage,
// vmcnt(4). Q pre-normalized/pre-scaled bf16; tree-summed l; bf16 o
// partials. STATIC max: partials combine exactly (o=sum, l=sum).
// =====================================================================
__global__ __launch_bounds__(256) void attn3(
    const short* __restrict__ q, const short* __restrict__ Knb,
    const short* __restrict__ Vtb,
    short* __restrict__ opart, float* __restrict__ lpart)
{
  int qb, h, bz;
  xcd_swizzle(qb, h, bz);
  const int b  = bz >> 1, s = bz & 1;
  const int g  = b >> 2;
  const int t  = threadIdx.x;
  const int w  = t >> 6;
  const int lane = t & 63;
  const int l31 = lane & 31, hi = lane >> 5;

  __shared__ short Kt[2][4096];
  __shared__ short Vt[2][4096];

  // ---- Q fragments: direct bf16 loads (pre-normalized, pre-scaled) ----
  const int qrow = qb * 128 + w * 32 + l31;
  const short* qp = q + ((long)b * N_ + qrow) * D_ + h * HD_ + hi * 8;
  bf16x8 qf[4];
  #pragma unroll
  for (int c = 0; c < 4; c++)
    qf[c] = *(const bf16x8*)&qp[c * 16];

  const short* Kg = Knb + (long)(g * H_ + h) * KVLEN * 64 + (long)s * 32 * 2048;
  const short* Vg = Vtb + (long)(g * H_ + h) * 64 * 2048 + (long)s * 32 * 2048;

  auto stage = [&](int buf, int i) {   // i = 64-kv chunk, 0..15
    GLOAD16(Kg + (long)i * 4096 + t * 8,        &Kt[buf][w * 512]);
    GLOAD16(Kg + (long)i * 4096 + 2048 + t * 8, &Kt[buf][2048 + w * 512]);
    GLOAD16(Vg + (long)i * 4096 + t * 8,        &Vt[buf][w * 512]);
    GLOAD16(Vg + (long)i * 4096 + 2048 + t * 8, &Vt[buf][2048 + w * 512]);
  };

  f32x16 oacc[2] = {};
  float l = 0.f;

  stage(0, 0);
  for (int i = 0; i < 16; ++i) {
    const int buf = i & 1;
    if (i + 1 < 16) {
      stage(buf ^ 1, i + 1);
      asm volatile("s_waitcnt vmcnt(4)" ::: "memory");
    } else {
      asm volatile("s_waitcnt vmcnt(0)" ::: "memory");
    }
    __builtin_amdgcn_s_barrier();
    __builtin_amdgcn_sched_barrier(0);

    #pragma unroll
    for (int ss = 0; ss < 2; ss++) {
      const short* Ktb = &Kt[buf][ss * 2048];
      const short* Vsb = &Vt[buf][ss * 2048];
      // ---- QK^T: scores[kv][q], pre-scaled via folded Q scale ----
      f32x16 sc = {};
      #pragma unroll
      for (int c = 0; c < 4; c++) {
        bf16x8 kfr = *(const bf16x8*)&Ktb[l31 * 64 + (((2 * c + hi) * 8) ^ ((l31 & 7) << 3))];
        sc = mfma_bf16(kfr, qf[c], sc);
      }
      // ---- softmax kernel: p~ = exp2(sc); l via balanced tree ----
      float p[16];
      #pragma unroll
      for (int r = 0; r < 16; r++)
        p[r] = exp2f(sc[r]);
      l += ((((p[0] + p[1]) + (p[2] + p[3])) + ((p[4] + p[5]) + (p[6] + p[7])))
         + (((p[8] + p[9]) + (p[10] + p[11])) + ((p[12] + p[13]) + (p[14] + p[15]))));
      // ---- pack P pairs to bf16 (cvt_pk), half-swap via permlane32 ----
      unsigned wd[8];
      #pragma unroll
      for (int i2 = 0; i2 < 8; i2++)
        asm("v_cvt_pk_bf16_f32 %0, %1, %2" : "=v"(wd[i2]) : "v"(p[2 * i2]), "v"(p[2 * i2 + 1]));
      u32x2 r0 = __builtin_amdgcn_permlane32_swap(wd[0], wd[2], false, false);
      u32x2 r1 = __builtin_amdgcn_permlane32_swap(wd[1], wd[3], false, false);
      u32x2 r2 = __builtin_amdgcn_permlane32_swap(wd[4], wd[6], false, false);
      u32x2 r3 = __builtin_amdgcn_permlane32_swap(wd[5], wd[7], false, false);
      int4 f0 = { (int)r0.x, (int)r1.x, (int)r0.y, (int)r1.y };
      int4 f1 = { (int)r2.x, (int)r3.x, (int)r2.y, (int)r3.y };
      // ---- PV ----
      #pragma unroll
      for (int n = 0; n < 2; n++) {
        const int d = n * 32 + l31;
        const int fd = (d >> 1) & 3;
        bf16x8 v0 = *(const bf16x8*)&Vsb[d * 32 + ((hi ^ fd) * 8)];
        bf16x8 v1 = *(const bf16x8*)&Vsb[d * 32 + (((2 | hi) ^ fd) * 8)];
        oacc[n] = mfma_bf16(__builtin_bit_cast(bf16x8, f0), v0, oacc[n]);
        oacc[n] = mfma_bf16(__builtin_bit_cast(bf16x8, f1), v1, oacc[n]);
      }
    }
    __builtin_amdgcn_s_barrier();
  }

  // ---- epilogue: write PARTIAL o (bf16, no divide) + l, plane s ----
  l += __shfl_xor(l, 32);
  #pragma unroll
  for (int r = 0; r < 16; r++) {
    const int qg = qb * 128 + w * 32 + (r & 3) + 8 * (r >> 2) + 4 * hi;
    short* op = opart + ((long)s * BN_ + b * N_ + qg) * D_ + h * HD_ + l31;
    op[0]  = bf16_rn(oacc[0][r]);
    op[32] = bf16_rn(oacc[1][r]);
  }
  if (hi == 0)
    lpart[((long)s * BN_ + b * N_ + qb * 128 + w * 32 + l31) * H_ + h] = l;
}

// =====================================================================
// attn_reduce2 — FUSED reduce + gate (bf16 partials; o hi-only).
//  A: o = (o0+o1)/(l0+l1) -> tiled bf16
//  B: G[0:5] = o·H5[:,j] + H5[1024][j]  (block reduce; G never stored)
//  C: gate[row] = 1 + mean_m sigmoid(sc*(G·mask[b][m] + G4))
// =====================================================================
__global__ __launch_bounds__(256) void attn_reduce2(
    const short* __restrict__ opart, const float* __restrict__ lpart,
    const float* __restrict__ H5, const float* __restrict__ mask,
    short* __restrict__ ohi, float* __restrict__ gate)
{
  __shared__ float red[4][5];
  __shared__ float Gs[5];
  __shared__ float sred[4];
  const int t = threadIdx.x;
  const int row = blockIdx.x;
  const int bb = row >> 9;
  const int col = t * 4;
  const int h   = col >> 6;
  // ---- A: combine 2 bf16 partial planes ----
  const float l = lpart[(long)row * H_ + h] + lpart[((long)BN_ + row) * H_ + h];
  const float inv = 1.f / l;
  s16x4 a4 = *(const s16x4*)&opart[(long)row * D_ + col];
  s16x4 b4 = *(const s16x4*)&opart[((long)BN_ + row) * D_ + col];
  float o4[4];
  #pragma unroll
  for (int c = 0; c < 4; c++)
    o4[c] = (bf2f(a4[c]) + bf2f(b4[c])) * inv;
  short hh[4];
  hh[0] = bf16_rn(o4[0]);  hh[1] = bf16_rn(o4[1]);
  hh[2] = bf16_rn(o4[2]);  hh[3] = bf16_rn(o4[3]);
  *(s16x4*)&ohi[tiled_off(row, col)] = *(s16x4*)hh;
  // ---- B: G = o . H5 (block reduce) ----
  float s[5] = {0.f, 0.f, 0.f, 0.f, 0.f};
  #pragma unroll
  for (int cc = 0; cc < 4; cc++) {
    const float* hp = &H5[(long)(col + cc) * 5];
    #pragma unroll
    for (int j = 0; j < 5; j++) s[j] = fmaf(o4[cc], hp[j], s[j]);
  }
  #pragma unroll
  for (int j = 0; j < 5; j++)
    #pragma unroll
    for (int m = 1; m < 64; m <<= 1) s[j] += __shfl_xor(s[j], m);
  const int w64 = t >> 6, lane = t & 63;
  if (lane == 0)
    #pragma unroll
    for (int j = 0; j < 5; j++) red[w64][j] = s[j];
  __syncthreads();
  if (t < 5) Gs[t] = red[0][t] + red[1][t] + red[2][t] + red[3][t] + H5[5120 + t];
  __syncthreads();
  const float g0 = Gs[0], g1 = Gs[1], g2 = Gs[2], g3 = Gs[3], g4 = Gs[4];
  // ---- C: gate via 512 sigmoids spread over the block ----
  const float sc = 0.125f / 16.f;       // SCALE/H
  const float* mrow = mask + (long)bb * N_ * NI_;
  float sg = 0.f;
  #pragma unroll
  for (int q = 0; q < 2; q++) {
    const float4 mk = *(const float4*)&mrow[(t * 2 + q) * 4];
    const float z = fmaf(g0, mk.x, fmaf(g1, mk.y, fmaf(g2, mk.z, fmaf(g3, mk.w, g4))));
    sg += 1.f / (1.f + __expf(-z * sc));
  }
  #pragma unroll
  for (int m = 1; m < 64; m <<= 1) sg += __shfl_xor(sg, m);
  if (lane == 0) sred[w64] = sg;
  __syncthreads();
  if (t == 0)
    gate[row] = 1.f + (sred[0] + sred[1] + sred[2] + sred[3]) * (1.f / 512.f);
}

// =====================================================================
extern "C" void kernel_launch(void* const* d_in, const int* in_sizes, int n_in,
                              void* d_out, int out_size, void* d_ws, size_t ws_size,
                              hipStream_t stream)
{
  const float* x    = (const float*)d_in[0];
  const float* mask = (const float*)d_in[1];
  const float* Wq   = (const float*)d_in[2];
  const float* bq   = (const float*)d_in[3];
  const float* Wk   = (const float*)d_in[4];
  const float* bk   = (const float*)d_in[5];
  const float* Wv   = (const float*)d_in[6];
  const float* bv   = (const float*)d_in[7];
  const float* Wo   = (const float*)d_in[8];
  const float* bo   = (const float*)d_in[9];
  const float* Wiq  = (const float*)d_in[10];
  const float* biq  = (const float*)d_in[11];
  const float* Wik  = (const float*)d_in[12];
  const float* bik  = (const float*)d_in[13];
  const float* emb  = (const float*)d_in[14];
  const float* qnw  = (const float*)d_in[15];
  const float* knw  = (const float*)d_in[16];
  float* out = (float*)d_out;

  // Workspace (within the round-9-proven footprint).
  // Lifetime audit (launch #):
  //  [0,SZ)     Qnb bf16 (w:5(QKV z=0 epi) r:6) -> ohi bf16 (w:7 r:8)
  //  [SZ,2SZ)   opart bf16 [2][BN][D] shorts (w:6 r:7). Dead during QKV.
  //  [3SZ,4SZ)  Knb bf16 (w:5(QKV z=1 epi) r:6). Dead during staging.
  //  [4SZ,4.5SZ) xhi: x tiled bf16 (w:4 r:5)
  //  [4.5SZ,5SZ) Vtb bf16 (w:5(QKV z=2 epi) r:6) — overlays dead xlo
  //  Wbig_hi:   QKV weights (w:4 r:5) -> gate + lpart[2] (w:7/6 r:8/7)
  //  Wbig_lo:   WoH (w:4 r:8) | F4 (w:2 r:3) | H5 (w:3 r:7) | F4p (w:1 r:2)
  float* ws = (float*)d_ws;
  const size_t SZ = (size_t)BN_ * D_;
  short* Qnb  = (short*)ws;             // [BN][1024] bf16 (normalized q)
  short* ohi  = (short*)ws;             // post-attn3: o bf16 tiled
  short* opart = (short*)(ws + SZ);     // [2][BN][D] bf16 attn partials
  short* Knb  = (short*)(ws + 3 * SZ);  // [2][16][2048][64] bf16
  short* xhi  = (short*)(ws + 4 * SZ);
  short* Vtb  = xhi + SZ;               // [2][16][64][64][32] bf16
  short* Wbig_hi = (short*)(ws + 5 * SZ);
  short* Wbig_lo = Wbig_hi + (size_t)3 * D_ * D_;
  float* gate  = (float*)Wbig_hi;                       // [BN] (post-QKV)
  float* lpart = gate + BN_;                            // [2][BN][16]
  short* WoH = Wbig_lo;                                 // [D][D] tiled
  float* F4  = (float*)(Wbig_lo + (size_t)D_ * D_);     // [4][1024]
  float* H5  = F4 + 4 * D_;                             // [1025][5]
  float* F4p = H5 + 1025 * 5;                           // [64][4][1024]

  const dim3 blk(256);

  // 1-3) gate-path algebra prep (rank-5 collapse), parallel grids
  fprep_p<<<dim3(4, 64), blk, 0, stream>>>(Wik, emb, F4p);
  freduce<<<dim3(16), blk, 0, stream>>>(F4p, F4);
  hprep2<<<dim3(1025), blk, 0, stream>>>(Wiq, F4, bik, biq, H5);

  // 4) weight prep (Wq,Wk,Wv,Wo) + x -> tiled bf16, ONE dispatch
  wsplitAll<<<dim3(16, 16, 8), blk, 0, stream>>>(
      Wq, Wk, Wv, Wo, x, Wbig_hi, WoH, xhi);

  // 5) fused QKV projection; Q-norm -> Qnb, K-norm -> Knb, V -> Vtb
  mfgemm2<6><<<dim3(8, 32, 3), blk, 0, stream>>>(
      xhi, Wbig_hi, bq, bk, bv,
      nullptr, Qnb, Knb, Vtb, qnw, knw, 8, 0, nullptr);

  // 6) attention, KV-split x2, KVBLK=64 -> bf16 partials
  attn3<<<dim3(N_ / 128, H_, B_ * 2), blk, 0, stream>>>(
      Qnb, Knb, Vtb, opart, lpart);

  // 7) combine partials -> o bf16 (over dead Qnb region), gate in-block
  attn_reduce2<<<BN_, blk, 0, stream>>>(opart, lpart, H5, mask, ohi, gate);

  // 8) final: gate[row]*(o@Wo) + bo -> d_out (plain bf16)
  mfgemm2<2><<<dim3(8, 32, 1), blk, 0, stream>>>(
      ohi, Wbig_lo, bo, nullptr, nullptr,
      out, nullptr, nullptr, nullptr, nullptr, nullptr, 0, 0, gate);
}